// Round 1
// baseline (76.939 us; speedup 1.0000x reference)
//
#include <hip/hip_runtime.h>

// out[b,c] = sum_k w[b,k] * BivariateNormalPDF(X[b,c]; params[b,k])
// B=512, K=64, C=2048.
//
// Round 13: two-kernel SGPR-coefficient scheme.
//  K1 (coef_kernel): per (b,k) compute Horner/log2-domain coefficients
//     A,B,C,D,E,F (w folded into F) and store 8 floats into d_ws packed as
//     pairs (C,D),(B,E),(A,F) -- pairing chosen so each v_pk_fma_f32 in the
//     main loop reads exactly ONE sgpr pair (1-SGPR-per-VALU rule).
//  K2 (mixture_main): coefficients come in via UNIFORM loads -> s_load ->
//     SGPR pairs consumed directly by VOP3P op_sel splats. Zero LDS, zero
//     per-iter lgkmcnt on the vector path. 2 pts/thread, 2048 blocks ->
//     8 blocks/CU -> 8 waves/SIMD for latency cover.
//   u = A*x + (C*y + D);  v = B*y + E;  e = x*u + (y*v + F);  acc += exp2(e)
//   per k per thread: 5 pk_fma + 1 pk_add + 2 v_exp_f32, nothing else.

typedef float v2f __attribute__((ext_vector_type(2)));
typedef unsigned long long u64;

constexpr int B = 512;
constexpr int K = 64;
constexpr int C = 2048;
constexpr int BLOCK = 256;
constexpr int QUARTERS = 4;          // each batch's C range split across 4 blocks
constexpr int CQ = C / QUARTERS;     // 512 points per block -> 2 per thread

__global__ __launch_bounds__(BLOCK) void coef_kernel(
    const float* __restrict__ mo,    // (B, K, 6)
    float* __restrict__ coef)        // (B*K, 8) : [C,D,B,E,A,F,0,0]
{
    const int i = blockIdx.x * BLOCK + threadIdx.x;   // 0 .. B*K-1
    const float* p6 = mo + (size_t)i * 6;
    const float w  = p6[0];
    const float m1 = p6[1];
    const float m2 = p6[2];
    const float s1 = p6[3];
    const float s2 = p6[4];
    const float r  = p6[5];

    const float omr2 = fmaf(-r, r, 1.0f);
    const float inv  = 1.0f / omr2;
    const float g    = 0.7213475204444817f * inv;   // 0.5*log2(e)/omr2
    const float i1   = 1.0f / s1;
    const float i2   = 1.0f / s2;
    const float p    = g * i1 * i1;
    const float q    = g * i2 * i2;
    const float s    = 2.0f * r * g * i1 * i2;
    const float A    = -p;
    const float Bc   = -q;
    const float Cc   = s;
    const float D    = fmaf(2.0f * p, m1, -s * m2);
    const float E    = fmaf(2.0f * q, m2, -s * m1);
    const float wn   = w * 0.15915494309189535f * i1 * i2 * sqrtf(inv);
    const float L    = log2f(fmaxf(wn, 1e-37f));
    const float F    = fmaf(-p, m1 * m1, fmaf(-q, m2 * m2, fmaf(s, m1 * m2, L)));

    float4* cp = (float4*)(coef + (size_t)i * 8);
    cp[0] = make_float4(Cc, D, Bc, E);   // pair0 = (C,D), pair1 = (B,E)
    cp[1] = make_float4(A, F, 0.0f, 0.0f); // pair2 = (A,F)
}

__global__ __launch_bounds__(BLOCK, 8) void mixture_main(
    const float* __restrict__ coef,  // (B*K, 8)
    const float* __restrict__ X,     // (B, C, 2)
    float* __restrict__ out)         // (B, C)
{
    const int bid = blockIdx.x;
    const int b   = bid >> 2;        // uniform
    const int q   = bid & 3;
    const int t   = threadIdx.x;

    // 2 points/thread: one coalesced float4 load = (x0,y0,x1,y1)
    const float4 xv = ((const float4*)(X + ((size_t)b * C + (size_t)q * CQ) * 2))[t];
    const v2f xp = { xv.x, xv.z };
    const v2f yp = { xv.y, xv.w };
    v2f acc = { 0.0f, 0.0f };

    // Block-uniform coefficient stream -> scalar loads -> SGPR pairs.
    const u64* cb = (const u64*)coef + (size_t)b * (K * 4);

#pragma unroll 4
    for (int k = 0; k < K; ++k) {
        const u64 pCD = cb[4 * k + 0];   // lo=C  hi=D
        const u64 pBE = cb[4 * k + 1];   // lo=B  hi=E
        const u64 pAF = cb[4 * k + 2];   // lo=A  hi=F

        v2f u, vv, e;
        // u = splat(C)*y + splat(D)
        asm("v_pk_fma_f32 %0, %1, %2, %1 op_sel:[0,0,1] op_sel_hi:[0,1,1]"
            : "=v"(u) : "s"(pCD), "v"(yp));
        // u = splat(A)*x + u
        asm("v_pk_fma_f32 %0, %1, %2, %0 op_sel:[0,0,0] op_sel_hi:[0,1,1]"
            : "+v"(u) : "s"(pAF), "v"(xp));
        // vv = splat(B)*y + splat(E)
        asm("v_pk_fma_f32 %0, %1, %2, %1 op_sel:[0,0,1] op_sel_hi:[0,1,1]"
            : "=v"(vv) : "s"(pBE), "v"(yp));
        // e = y*vv + splat(F)
        asm("v_pk_fma_f32 %0, %1, %2, %3 op_sel:[0,0,1] op_sel_hi:[1,1,1]"
            : "=v"(e) : "v"(yp), "v"(vv), "s"(pAF));
        // e = x*u + e
        e = __builtin_elementwise_fma(xp, u, e);

        v2f ex;
        ex.x = __builtin_amdgcn_exp2f(e.x);
        ex.y = __builtin_amdgcn_exp2f(e.y);
        acc = acc + ex;
    }

    ((float2*)(out + (size_t)b * C + (size_t)q * CQ))[t] = make_float2(acc.x, acc.y);
}

extern "C" void kernel_launch(void* const* d_in, const int* in_sizes, int n_in,
                              void* d_out, int out_size, void* d_ws, size_t ws_size,
                              hipStream_t stream) {
    const float* mo = (const float*)d_in[0];   // (B,K,6)
    const float* X  = (const float*)d_in[1];   // (B,C,2)
    float* out      = (float*)d_out;           // (B,C)
    float* coef     = (float*)d_ws;            // needs B*K*8*4 = 1 MB

    coef_kernel<<<dim3(B * K / BLOCK), dim3(BLOCK), 0, stream>>>(mo, coef);
    mixture_main<<<dim3(B * QUARTERS), dim3(BLOCK), 0, stream>>>(coef, X, out);
}

// Round 2
// 71.254 us; speedup vs baseline: 1.0798x; 1.0798x over previous
//
#include <hip/hip_runtime.h>

// out[b,c] = sum_k w[b,k] * BivariateNormalPDF(X[b,c]; params[b,k])
// B=512, K=64, C=2048.
//
// Round 14: restore of the R12 best (69.8/70.26 us harness-verified).
// R13's two-kernel SGPR-coefficient experiment regressed (+6.7 us): the
// extra dependent launch + coef kernel + per-iter s_load lgkmcnt waits cost
// more than the LDS broadcast reads they replaced (which were already
// hidden by 4-wave TLP).
//
// Structure: 1024 blocks, 256 thr, 4 pts/thread, 4 blocks/CU, LDS
// [A,B,C,D][E,F,-,-] per k, 2 ds_read_b128/k-iter; inner quadratic via
// VOP3P op_sel inline asm (scalar coefficients splatted INSIDE each
// v_pk_fma_f32 from the raw ds_read result registers -> zero splat movs).
// Horner form, log2 domain, wn folded into F:
//   u = A*x + (C*y + D);  v = B*y + E;  e = x*u + (y*v + F);
//   acc += exp2(e)   [per packed pair: 5 pk_fma + 1 pk_add + 2 v_exp]
// Per k-iter per wave: 12 pk + 4 exp + 2 ds_read_b128, nothing else.
// Exec floors: trans 3.4 us, VALU 2.6 us, HBM 2.1 us -> trans-bound.

typedef float v2f __attribute__((ext_vector_type(2)));

constexpr int B = 512;
constexpr int K = 64;
constexpr int C = 2048;
constexpr int BLOCK = 256;
constexpr int HALVES = 2;        // each batch's C range split across 2 blocks
constexpr int CH = C / HALVES;   // 1024 points per block -> 4 per thread

__global__ __launch_bounds__(BLOCK, 4) void mixture_kernel(
    const float* __restrict__ mo,   // (B, K, 6)
    const float* __restrict__ X,    // (B, C, 2)
    float* __restrict__ out)        // (B, C)
{
    __shared__ float4 P[K][2];      // [A,B,C,D], [E,F,-,-]

    const int bid = blockIdx.x;
    const int b   = bid >> 1;
    const int h   = bid & 1;
    const int t   = threadIdx.x;

    if (t < K) {
        const float* p6 = mo + ((size_t)(b * K + t)) * 6;
        const float w  = p6[0];
        const float m1 = p6[1];
        const float m2 = p6[2];
        const float s1 = p6[3];
        const float s2 = p6[4];
        const float r  = p6[5];

        const float omr2 = fmaf(-r, r, 1.0f);
        const float inv  = 1.0f / omr2;
        const float g    = 0.7213475204444817f * inv;   // 0.5*log2(e)/omr2
        const float i1   = 1.0f / s1;
        const float i2   = 1.0f / s2;
        const float p    = g * i1 * i1;
        const float q    = g * i2 * i2;
        const float s    = 2.0f * r * g * i1 * i2;
        const float A    = -p;
        const float Bc   = -q;
        const float Cc   = s;
        const float D    = fmaf(2.0f * p, m1, -s * m2);
        const float E    = fmaf(2.0f * q, m2, -s * m1);
        const float wn   = w * 0.15915494309189535f * i1 * i2 * sqrtf(inv);
        const float L    = log2f(fmaxf(wn, 1e-37f));
        const float F    = fmaf(-p, m1 * m1, fmaf(-q, m2 * m2, fmaf(s, m1 * m2, L)));

        P[t][0] = make_float4(A, Bc, Cc, D);
        P[t][1] = make_float4(E, F, 0.0f, 0.0f);
    }
    __syncthreads();

    // 4 points/thread: 2 coalesced float4 loads, repacked (x,x)/(y,y).
    const float4* Xb = (const float4*)(X + ((size_t)b * C + (size_t)h * CH) * 2);
    const float4 xv0 = Xb[t];
    const float4 xv1 = Xb[t + BLOCK];

    const v2f xp[2] = { {xv0.x, xv0.z}, {xv1.x, xv1.z} };
    const v2f yp[2] = { {xv0.y, xv0.w}, {xv1.y, xv1.w} };
    v2f acc[2] = { {0.0f, 0.0f}, {0.0f, 0.0f} };

#pragma unroll 4
    for (int k = 0; k < K; ++k) {
        const float4 c0 = P[k][0];           // A,B | C,D  (two VGPR pairs)
        const float4 c1 = P[k][1];           // E,F | -,-
        const v2f cAB = { c0.x, c0.y };      // subregister pair of c0
        const v2f cCD = { c0.z, c0.w };
        const v2f cEF = { c1.x, c1.y };

#pragma unroll
        for (int j = 0; j < 2; ++j) {
            v2f u, vv, e;
            // u = splat(C)*y + splat(D)     [C=lo(cCD), D=hi(cCD)]
            asm("v_pk_fma_f32 %0, %1, %2, %1 op_sel:[0,0,1] op_sel_hi:[0,1,1]"
                : "=v"(u) : "v"(cCD), "v"(yp[j]));
            // u = splat(A)*x + u            [A=lo(cAB)]
            asm("v_pk_fma_f32 %0, %1, %2, %0 op_sel:[0,0,0] op_sel_hi:[0,1,1]"
                : "+v"(u) : "v"(cAB), "v"(xp[j]));
            // vv = splat(B)*y + splat(E)    [B=hi(cAB), E=lo(cEF)]
            asm("v_pk_fma_f32 %0, %1, %2, %3 op_sel:[1,0,0] op_sel_hi:[1,1,0]"
                : "=v"(vv) : "v"(cAB), "v"(yp[j]), "v"(cEF));
            // e = y*vv + splat(F)           [F=hi(cEF)]
            asm("v_pk_fma_f32 %0, %1, %2, %3 op_sel:[0,0,1] op_sel_hi:[1,1,1]"
                : "=v"(e) : "v"(yp[j]), "v"(vv), "v"(cEF));
            // e = x*u + e  (plain packed fma, no op_sel needed)
            e = __builtin_elementwise_fma(xp[j], u, e);
            v2f ex;
            ex.x = __builtin_amdgcn_exp2f(e.x);
            ex.y = __builtin_amdgcn_exp2f(e.y);
            acc[j] = acc[j] + ex;
        }
    }

    float2* ob = (float2*)(out + (size_t)b * C + (size_t)h * CH);
    ob[t]         = make_float2(acc[0].x, acc[0].y);
    ob[t + BLOCK] = make_float2(acc[1].x, acc[1].y);
}

extern "C" void kernel_launch(void* const* d_in, const int* in_sizes, int n_in,
                              void* d_out, int out_size, void* d_ws, size_t ws_size,
                              hipStream_t stream) {
    const float* mo = (const float*)d_in[0];   // (B,K,6)
    const float* X  = (const float*)d_in[1];   // (B,C,2)
    float* out      = (float*)d_out;           // (B,C)

    mixture_kernel<<<dim3(B * HALVES), dim3(BLOCK), 0, stream>>>(mo, X, out);
}